// Round 1
// baseline (2929.436 us; speedup 1.0000x reference)
//
#include <hip/hip_runtime.h>
#include <math.h>

#define Bb   4
#define Tt   2048
#define DIN  1024
#define DOUT 1024
#define NH   16
#define HD   64

// ---------------------------------------------------------------------------
// Tiled fp32 GEMM: C[M,N] = A[M,K] @ W[K,N] (+ bias). BM=BN=64, BK=16,
// 256 threads, 4x4 micro-tile per thread, float4 global loads, padded LDS.
// ---------------------------------------------------------------------------
template <bool BIAS>
__global__ __launch_bounds__(256) void gemm_f32(
    const float* __restrict__ A, const float* __restrict__ W,
    const float* __restrict__ bias, float* __restrict__ C,
    int M, int N, int Kd) {
  constexpr int BM = 64, BN = 64, BK = 16;
  __shared__ float As[BK][BM + 4];  // stored transposed: As[k][m]
  __shared__ float Bs[BK][BN + 4];

  const int tid = threadIdx.x;
  const int bm = blockIdx.x * BM;
  const int bn = blockIdx.y * BN;
  const int ty = tid >> 4, tx = tid & 15;   // 16x16 thread grid
  const int r0 = ty * 4, c0 = tx * 4;

  // A tile load: 64 rows x 16 k, one float4 per thread
  const int arow = tid >> 2, ac0 = (tid & 3) * 4;
  // W tile load: 16 k-rows x 64 cols, one float4 per thread
  const int brow = tid >> 4, bc0 = (tid & 15) * 4;

  const float* Ap = A + (size_t)(bm + arow) * Kd + ac0;
  const float* Wp = W + (size_t)brow * N + bn + bc0;

  float acc[4][4] = {};

  for (int k0 = 0; k0 < Kd; k0 += BK) {
    float4 a = *(const float4*)(Ap + k0);
    float4 b = *(const float4*)(Wp + (size_t)k0 * N);
    __syncthreads();  // previous iteration's readers done
    As[ac0 + 0][arow] = a.x;
    As[ac0 + 1][arow] = a.y;
    As[ac0 + 2][arow] = a.z;
    As[ac0 + 3][arow] = a.w;
    *(float4*)&Bs[brow][bc0] = b;
    __syncthreads();
#pragma unroll
    for (int k = 0; k < BK; ++k) {
      float4 av = *(const float4*)&As[k][r0];
      float4 bv = *(const float4*)&Bs[k][c0];
      float am[4] = {av.x, av.y, av.z, av.w};
      float bm_[4] = {bv.x, bv.y, bv.z, bv.w};
#pragma unroll
      for (int i = 0; i < 4; ++i)
#pragma unroll
        for (int j = 0; j < 4; ++j)
          acc[i][j] = fmaf(am[i], bm_[j], acc[i][j]);
    }
  }

#pragma unroll
  for (int i = 0; i < 4; ++i) {
    float4 v;
    float* vp = &v.x;
#pragma unroll
    for (int j = 0; j < 4; ++j) {
      float val = acc[i][j];
      if (BIAS) val += bias[bn + c0 + j];
      vp[j] = val;
    }
    *(float4*)&C[(size_t)(bm + r0 + i) * N + bn + c0] = v;
  }
}

// ---------------------------------------------------------------------------
// Causal flash attention, fp32. Q/K/V stored as [B, T, H, HD].
// Grid: (T/64 q-tiles, B*H). Block: 256 threads.
// Each block: 64 q-rows, iterates kv-tiles 0..qt with online softmax.
// Thread (ty,tx) owns O[r0..r0+3][c0..c0+3] (4 rows x 4 dims).
// ---------------------------------------------------------------------------
__global__ __launch_bounds__(256) void attn_f32(
    const float* __restrict__ Q, const float* __restrict__ K,
    const float* __restrict__ V, float* __restrict__ Ctx) {
  const int qt = blockIdx.x;            // 0..31
  const int bh = blockIdx.y;            // 0..63
  const int b = bh >> 4, h = bh & 15;

  __shared__ float Qs[64][HD + 4];
  __shared__ float Ks[64][HD + 4];
  __shared__ float Vs[64][HD + 4];
  __shared__ float Ss[64][64 + 4];
  __shared__ float mrow[64], lrow[64], arow_s[64];

  const int tid = threadIdx.x;
  const int ty = tid >> 4, tx = tid & 15;
  const int r0 = ty * 4, c0 = tx * 4;

  // tile-load mapping: thread loads one 64B chunk (4 float4) of one row
  const int lr = tid >> 2, lc0 = (tid & 3) * 16;

  // ---- load Q tile ----
  {
    const size_t qb = ((size_t)(b * Tt + qt * 64 + lr) * NH + h) * HD + lc0;
    float4 q0 = *(const float4*)&Q[qb + 0];
    float4 q1 = *(const float4*)&Q[qb + 4];
    float4 q2 = *(const float4*)&Q[qb + 8];
    float4 q3 = *(const float4*)&Q[qb + 12];
    *(float4*)&Qs[lr][lc0 + 0]  = q0;
    *(float4*)&Qs[lr][lc0 + 4]  = q1;
    *(float4*)&Qs[lr][lc0 + 8]  = q2;
    *(float4*)&Qs[lr][lc0 + 12] = q3;
  }
  if (tid < 64) {
    mrow[tid] = -INFINITY;
    lrow[tid] = 0.0f;
  }

  float O[4][4] = {};

  __syncthreads();

  for (int kt = 0; kt <= qt; ++kt) {
    // issue K/V global loads early
    const size_t kb = ((size_t)(b * Tt + kt * 64 + lr) * NH + h) * HD + lc0;
    float4 k0v = *(const float4*)&K[kb + 0];
    float4 k1v = *(const float4*)&K[kb + 4];
    float4 k2v = *(const float4*)&K[kb + 8];
    float4 k3v = *(const float4*)&K[kb + 12];
    float4 v0v = *(const float4*)&V[kb + 0];
    float4 v1v = *(const float4*)&V[kb + 4];
    float4 v2v = *(const float4*)&V[kb + 8];
    float4 v3v = *(const float4*)&V[kb + 12];

    __syncthreads();  // previous iteration's consumers of Ks/Vs/Ss done
    *(float4*)&Ks[lr][lc0 + 0]  = k0v;
    *(float4*)&Ks[lr][lc0 + 4]  = k1v;
    *(float4*)&Ks[lr][lc0 + 8]  = k2v;
    *(float4*)&Ks[lr][lc0 + 12] = k3v;
    *(float4*)&Vs[lr][lc0 + 0]  = v0v;
    *(float4*)&Vs[lr][lc0 + 4]  = v1v;
    *(float4*)&Vs[lr][lc0 + 8]  = v2v;
    *(float4*)&Vs[lr][lc0 + 12] = v3v;
    __syncthreads();

    // ---- S = Q @ K^T (4x4 per thread) ----
    float s[4][4] = {};
#pragma unroll
    for (int k = 0; k < HD; k += 4) {
      float4 qv[4], kv[4];
#pragma unroll
      for (int i = 0; i < 4; ++i) qv[i] = *(const float4*)&Qs[r0 + i][k];
#pragma unroll
      for (int j = 0; j < 4; ++j) kv[j] = *(const float4*)&Ks[c0 + j][k];
#pragma unroll
      for (int i = 0; i < 4; ++i)
#pragma unroll
        for (int j = 0; j < 4; ++j) {
          s[i][j] = fmaf(qv[i].x, kv[j].x, s[i][j]);
          s[i][j] = fmaf(qv[i].y, kv[j].y, s[i][j]);
          s[i][j] = fmaf(qv[i].z, kv[j].z, s[i][j]);
          s[i][j] = fmaf(qv[i].w, kv[j].w, s[i][j]);
        }
    }
    const bool diag = (kt == qt);
#pragma unroll
    for (int i = 0; i < 4; ++i)
#pragma unroll
      for (int j = 0; j < 4; ++j) {
        float val = s[i][j] * 0.125f;  // 1/sqrt(64)
        if (diag && (c0 + j) > (r0 + i)) val = -INFINITY;
        Ss[r0 + i][c0 + j] = val;
      }
    __syncthreads();

    // ---- online softmax: 4 threads per row ----
    {
      const int r = tid >> 2, seg = (tid & 3) * 16;
      float mx = -INFINITY;
#pragma unroll
      for (int c = 0; c < 16; ++c) mx = fmaxf(mx, Ss[r][seg + c]);
      mx = fmaxf(mx, __shfl_xor(mx, 1));
      mx = fmaxf(mx, __shfl_xor(mx, 2));
      const float m_prev = mrow[r];
      const float m_new = fmaxf(m_prev, mx);
      float sum = 0.0f;
#pragma unroll
      for (int c = 0; c < 16; ++c) {
        float p = __expf(Ss[r][seg + c] - m_new);
        Ss[r][seg + c] = p;
        sum += p;
      }
      sum += __shfl_xor(sum, 1);
      sum += __shfl_xor(sum, 2);
      if ((tid & 3) == 0) {
        const float alpha = __expf(m_prev - m_new);
        arow_s[r] = alpha;
        lrow[r] = lrow[r] * alpha + sum;
        mrow[r] = m_new;
      }
    }
    __syncthreads();

    // ---- O = O*alpha + P @ V ----
    {
      float al[4];
#pragma unroll
      for (int i = 0; i < 4; ++i) al[i] = arow_s[r0 + i];
#pragma unroll
      for (int i = 0; i < 4; ++i)
#pragma unroll
        for (int j = 0; j < 4; ++j) O[i][j] *= al[i];
#pragma unroll 8
      for (int c = 0; c < 64; ++c) {
        float4 vv = *(const float4*)&Vs[c][c0];
        float vj[4] = {vv.x, vv.y, vv.z, vv.w};
        float p[4];
#pragma unroll
        for (int i = 0; i < 4; ++i) p[i] = Ss[r0 + i][c];
#pragma unroll
        for (int i = 0; i < 4; ++i)
#pragma unroll
          for (int j = 0; j < 4; ++j)
            O[i][j] = fmaf(p[i], vj[j], O[i][j]);
      }
    }
  }

  // ---- finalize: O /= l, store to Ctx [B,T,H,HD] ----
  float linv[4];
#pragma unroll
  for (int i = 0; i < 4; ++i) linv[i] = 1.0f / lrow[r0 + i];
#pragma unroll
  for (int i = 0; i < 4; ++i) {
    float4 v;
    v.x = O[i][0] * linv[i];
    v.y = O[i][1] * linv[i];
    v.z = O[i][2] * linv[i];
    v.w = O[i][3] * linv[i];
    *(float4*)&Ctx[((size_t)(b * Tt + qt * 64 + r0 + i) * NH + h) * HD + c0] = v;
  }
}

// ---------------------------------------------------------------------------
extern "C" void kernel_launch(void* const* d_in, const int* in_sizes, int n_in,
                              void* d_out, int out_size, void* d_ws, size_t ws_size,
                              hipStream_t stream) {
  const float* x  = (const float*)d_in[0];
  const float* Wq = (const float*)d_in[1];
  const float* Wk = (const float*)d_in[2];
  const float* Wv = (const float*)d_in[3];
  const float* Wo = (const float*)d_in[4];
  const float* bo = (const float*)d_in[5];
  float* out = (float*)d_out;

  const size_t NT = (size_t)Bb * Tt * DOUT;  // 8,388,608 elements (32 MiB each)
  float* Qw = (float*)d_ws;
  float* Kw = Qw + NT;
  float* Vw = Kw + NT;
  float* Cw = Vw + NT;

  const int M = Bb * Tt;  // 8192
  dim3 gg(M / 64, DOUT / 64);  // (128, 16)
  dim3 blk(256);

  gemm_f32<false><<<gg, blk, 0, stream>>>(x, Wq, nullptr, Qw, M, DOUT, DIN);
  gemm_f32<false><<<gg, blk, 0, stream>>>(x, Wk, nullptr, Kw, M, DOUT, DIN);
  gemm_f32<false><<<gg, blk, 0, stream>>>(x, Wv, nullptr, Vw, M, DOUT, DIN);

  attn_f32<<<dim3(Tt / 64, Bb * NH), blk, 0, stream>>>(Qw, Kw, Vw, Cw);

  gemm_f32<true><<<gg, blk, 0, stream>>>(Cw, Wo, bo, out, M, DOUT, DOUT);
}

// Round 3
// 543.249 us; speedup vs baseline: 5.3924x; 5.3924x over previous
//
#include <hip/hip_runtime.h>
#include <math.h>

#define Bb   4
#define Tt   2048
#define DIN  1024
#define DOUT 1024
#define NH   16
#define HD   64

typedef __attribute__((ext_vector_type(8))) short bf16x8;
typedef __attribute__((ext_vector_type(4))) float f32x4;
typedef __attribute__((ext_vector_type(4))) short short4v;

__device__ __forceinline__ short f2bf(float f) {
  union { float f; unsigned u; } v; v.f = f;
  unsigned r = v.u + 0x7FFFu + ((v.u >> 16) & 1u);
  return (short)(r >> 16);
}

#define MFMA16(a, b, c) __builtin_amdgcn_mfma_f32_16x16x32_bf16((a), (b), (c), 0, 0, 0)

// ---------------------------------------------------------------------------
// cvt_x: fp32 -> bf16, [B*T][DIN]
// ---------------------------------------------------------------------------
__global__ __launch_bounds__(256) void cvt_x(const float* __restrict__ x,
                                             short* __restrict__ xb) {
  const int i = (blockIdx.x * 256 + threadIdx.x) * 4;
  float4 v = *(const float4*)(x + i);
  short4v o;
  o.x = f2bf(v.x); o.y = f2bf(v.y); o.z = f2bf(v.z); o.w = f2bf(v.w);
  *(short4v*)(xb + i) = o;
}

// ---------------------------------------------------------------------------
// cvt_wt: W [K][N] fp32 -> Wt [N][K] bf16 (transpose+convert), 64x64 tiles.
// grid (N/64, K/64, 4)
// ---------------------------------------------------------------------------
__global__ __launch_bounds__(256) void cvt_wt(
    const float* __restrict__ W0, const float* __restrict__ W1,
    const float* __restrict__ W2, const float* __restrict__ W3,
    short* __restrict__ O0, short* __restrict__ O1,
    short* __restrict__ O2, short* __restrict__ O3) {
  const float* W = blockIdx.z == 0 ? W0 : blockIdx.z == 1 ? W1
                 : blockIdx.z == 2 ? W2 : W3;
  short* O = blockIdx.z == 0 ? O0 : blockIdx.z == 1 ? O1
           : blockIdx.z == 2 ? O2 : O3;
  __shared__ short t[64][65];
  const int n0 = blockIdx.x * 64, k0 = blockIdx.y * 64;
  const int tid = threadIdx.x;
#pragma unroll
  for (int i = 0; i < 16; ++i) {
    const int e = tid + 256 * i;
    const int k = e >> 6, n = e & 63;
    t[n][k] = f2bf(W[(size_t)(k0 + k) * DOUT + n0 + n]);
  }
  __syncthreads();
#pragma unroll
  for (int i = 0; i < 16; ++i) {
    const int e = tid + 256 * i;
    const int n = e >> 6, k = e & 63;
    O[(size_t)(n0 + n) * DIN + k0 + k] = t[n][k];
  }
}

// ---------------------------------------------------------------------------
// bf16 MFMA GEMM: C[M,N] = A[M,K] @ B  (B given transposed: Bt[N][K]).
// BM=BN=128, BK=32, 256 threads = 4 waves (2x2), wave tile 64x64 (4x4 frags).
// ---------------------------------------------------------------------------
template <bool F32OUT, bool BIAS>
__global__ __launch_bounds__(256) void gemm_bf16(
    const short* __restrict__ A, const short* __restrict__ Bt,
    const float* __restrict__ bias, void* __restrict__ Cout,
    int M, int N, int K) {
  constexpr int BM = 128, BN = 128, BK = 32;
  constexpr int LDT = BK + 8;  // 40 elems = 80B row stride (bank-spread)
  __shared__ short Asm[BM][LDT];
  __shared__ short Bsm[BN][LDT];

  const int tid = threadIdx.x;
  const int wid = tid >> 6, lane = tid & 63;
  const int lhi = lane >> 4, llo = lane & 15;
  const int bm = blockIdx.x * BM, bn = blockIdx.y * BN;
  const int wr = (wid >> 1) * 64, wc = (wid & 1) * 64;

  // staging map: thread covers 32B (16 bf16) of one row
  const int sr = tid >> 1, so = (tid & 1) * 16;
  const short* Ag = A + (size_t)(bm + sr) * K + so;
  const short* Bg = Bt + (size_t)(bn + sr) * K + so;

  f32x4 acc[4][4];
#pragma unroll
  for (int i = 0; i < 4; ++i)
#pragma unroll
    for (int j = 0; j < 4; ++j)
#pragma unroll
      for (int r = 0; r < 4; ++r) acc[i][j][r] = 0.0f;

  for (int k0 = 0; k0 < K; k0 += BK) {
    bf16x8 a0 = *(const bf16x8*)(Ag + k0);
    bf16x8 a1 = *(const bf16x8*)(Ag + k0 + 8);
    bf16x8 b0 = *(const bf16x8*)(Bg + k0);
    bf16x8 b1 = *(const bf16x8*)(Bg + k0 + 8);
    __syncthreads();
    *(bf16x8*)&Asm[sr][so] = a0;
    *(bf16x8*)&Asm[sr][so + 8] = a1;
    *(bf16x8*)&Bsm[sr][so] = b0;
    *(bf16x8*)&Bsm[sr][so + 8] = b1;
    __syncthreads();

    const int fk = lhi * 8;
    bf16x8 af[4], bfr[4];
#pragma unroll
    for (int i = 0; i < 4; ++i)
      af[i] = *(const bf16x8*)&Asm[wr + i * 16 + llo][fk];
#pragma unroll
    for (int j = 0; j < 4; ++j)
      bfr[j] = *(const bf16x8*)&Bsm[wc + j * 16 + llo][fk];
#pragma unroll
    for (int i = 0; i < 4; ++i)
#pragma unroll
      for (int j = 0; j < 4; ++j)
        acc[i][j] = MFMA16(af[i], bfr[j], acc[i][j]);
  }

#pragma unroll
  for (int i = 0; i < 4; ++i)
#pragma unroll
    for (int j = 0; j < 4; ++j)
#pragma unroll
      for (int r = 0; r < 4; ++r) {
        const int row = bm + wr + i * 16 + lhi * 4 + r;
        const int col = bn + wc + j * 16 + llo;
        float v = acc[i][j][r];
        if (BIAS) v += bias[col];
        if (F32OUT)
          ((float*)Cout)[(size_t)row * N + col] = v;
        else
          ((short*)Cout)[(size_t)row * N + col] = f2bf(v);
      }
}

// ---------------------------------------------------------------------------
// Causal flash attention, bf16 MFMA. Q/K/V: [B*T][DOUT] bf16, head at h*64.
// Grid (T/64, B*NH). 256 threads = 4 waves; wave w owns q-rows w*16..w*16+15.
// KV tiles of 64; online softmax in registers; P via per-wave LDS.
// ---------------------------------------------------------------------------
__global__ __launch_bounds__(256) void attn_bf16(
    const short* __restrict__ Q, const short* __restrict__ K,
    const short* __restrict__ V, short* __restrict__ Ctx) {
  constexpr int LDK = HD + 8;  // 72 elems, 144B stride
  __shared__ short Ks[64][LDK];
  __shared__ short Vt[HD][64 + 8];      // V transposed: [hd][kv]
  __shared__ short Ps[4][16][LDK];      // per-wave P tile [qrow][kv]

  const int qt = blockIdx.x, bh = blockIdx.y;
  const int b = bh >> 4, h = bh & 15;
  const int tid = threadIdx.x;
  const int wid = tid >> 6, lane = tid & 63;
  const int lhi = lane >> 4, llo = lane & 15;

  const size_t base_bt = (size_t)b * Tt;
  const int headoff = h * HD;

  // ---- hoist Q fragments to registers (A-frag: row=llo, k=8*lhi[+32]) ----
  const int qrow = qt * 64 + wid * 16 + llo;
  const short* Qp = Q + (base_bt + qrow) * DOUT + headoff;
  bf16x8 qf0 = *(const bf16x8*)(Qp + 8 * lhi);
  bf16x8 qf1 = *(const bf16x8*)(Qp + 32 + 8 * lhi);

  float m_r[4], l_r[4];
  f32x4 oacc[4];
#pragma unroll
  for (int r = 0; r < 4; ++r) { m_r[r] = -1e30f; l_r[r] = 0.0f; }
#pragma unroll
  for (int j = 0; j < 4; ++j)
#pragma unroll
    for (int r = 0; r < 4; ++r) oacc[j][r] = 0.0f;

  const float sc = 0.125f * 1.44269504089f;  // (1/sqrt(HD)) * log2(e)

  // staging map: chunk c covers K/V row c>>3, elems (c&7)*8..+7; c = tid, tid+256
  const int r1 = tid >> 3, o1 = (tid & 7) * 8;

  for (int kt = 0; kt <= qt; ++kt) {
    const short* Kg = K + (base_bt + kt * 64 + r1) * DOUT + headoff + o1;
    const short* Vg = V + (base_bt + kt * 64 + r1) * DOUT + headoff + o1;
    bf16x8 kc0 = *(const bf16x8*)(Kg);
    bf16x8 kc1 = *(const bf16x8*)(Kg + 32 * DOUT);
    bf16x8 vc0 = *(const bf16x8*)(Vg);
    bf16x8 vc1 = *(const bf16x8*)(Vg + 32 * DOUT);

    __syncthreads();  // previous iteration's consumers done
    *(bf16x8*)&Ks[r1][o1] = kc0;
    *(bf16x8*)&Ks[r1 + 32][o1] = kc1;
#pragma unroll
    for (int e = 0; e < 8; ++e) {
      Vt[o1 + e][r1] = vc0[e];
      Vt[o1 + e][r1 + 32] = vc1[e];
    }
    __syncthreads();

    // ---- S = Q @ K^T : per wave 16x64 = 4 colblocks, 2 k-steps ----
    f32x4 s[4];
#pragma unroll
    for (int j = 0; j < 4; ++j) {
      f32x4 a;
#pragma unroll
      for (int r = 0; r < 4; ++r) a[r] = 0.0f;
      bf16x8 kf0 = *(const bf16x8*)&Ks[j * 16 + llo][8 * lhi];
      bf16x8 kf1 = *(const bf16x8*)&Ks[j * 16 + llo][32 + 8 * lhi];
      a = MFMA16(qf0, kf0, a);
      a = MFMA16(qf1, kf1, a);
      s[j] = a;
    }

    // ---- causal mask on diagonal tile ----
    if (kt == qt) {
#pragma unroll
      for (int j = 0; j < 4; ++j)
#pragma unroll
        for (int r = 0; r < 4; ++r) {
          const int qr = wid * 16 + lhi * 4 + r;
          const int kc = j * 16 + llo;
          if (kc > qr) s[j][r] = -1e30f;
        }
    }

    // ---- online softmax (rows live in 16-lane groups) ----
    float mx[4];
#pragma unroll
    for (int r = 0; r < 4; ++r)
      mx[r] = fmaxf(fmaxf(s[0][r], s[1][r]), fmaxf(s[2][r], s[3][r]));
#pragma unroll
    for (int d = 1; d < 16; d <<= 1) {
#pragma unroll
      for (int r = 0; r < 4; ++r) mx[r] = fmaxf(mx[r], __shfl_xor(mx[r], d));
    }
    float mnew[4], alpha[4], rsum[4];
#pragma unroll
    for (int r = 0; r < 4; ++r) {
      mnew[r] = fmaxf(m_r[r], mx[r]);
      alpha[r] = exp2f((m_r[r] - mnew[r]) * sc);
      rsum[r] = 0.0f;
    }
#pragma unroll
    for (int j = 0; j < 4; ++j)
#pragma unroll
      for (int r = 0; r < 4; ++r) {
        const float p = exp2f((s[j][r] - mnew[r]) * sc);
        s[j][r] = p;
        rsum[r] += p;
      }
#pragma unroll
    for (int d = 1; d < 16; d <<= 1) {
#pragma unroll
      for (int r = 0; r < 4; ++r) rsum[r] += __shfl_xor(rsum[r], d);
    }
#pragma unroll
    for (int r = 0; r < 4; ++r) {
      l_r[r] = l_r[r] * alpha[r] + rsum[r];
      m_r[r] = mnew[r];
    }
#pragma unroll
    for (int j = 0; j < 4; ++j)
#pragma unroll
      for (int r = 0; r < 4; ++r) oacc[j][r] *= alpha[r];

    // ---- P -> bf16 -> per-wave LDS (to reach MFMA A layout) ----
#pragma unroll
    for (int j = 0; j < 4; ++j)
#pragma unroll
      for (int r = 0; r < 4; ++r)
        Ps[wid][lhi * 4 + r][j * 16 + llo] = f2bf(s[j][r]);

    // ---- O += P @ V ----
#pragma unroll
    for (int ks = 0; ks < 2; ++ks) {
      bf16x8 paf = *(const bf16x8*)&Ps[wid][llo][8 * lhi + 32 * ks];
#pragma unroll
      for (int j = 0; j < 4; ++j) {
        bf16x8 vf = *(const bf16x8*)&Vt[j * 16 + llo][8 * lhi + 32 * ks];
        oacc[j] = MFMA16(paf, vf, oacc[j]);
      }
    }
  }

  // ---- finalize ----
#pragma unroll
  for (int j = 0; j < 4; ++j)
#pragma unroll
    for (int r = 0; r < 4; ++r) {
      const int row = qt * 64 + wid * 16 + lhi * 4 + r;
      const int col = headoff + j * 16 + llo;
      Ctx[(base_bt + row) * DOUT + col] = f2bf(oacc[j][r] / l_r[r]);
    }
}

// ---------------------------------------------------------------------------
extern "C" void kernel_launch(void* const* d_in, const int* in_sizes, int n_in,
                              void* d_out, int out_size, void* d_ws, size_t ws_size,
                              hipStream_t stream) {
  const float* x  = (const float*)d_in[0];
  const float* Wq = (const float*)d_in[1];
  const float* Wk = (const float*)d_in[2];
  const float* Wv = (const float*)d_in[3];
  const float* Wo = (const float*)d_in[4];
  const float* bo = (const float*)d_in[5];
  float* out = (float*)d_out;

  const size_t NTD = (size_t)Bb * Tt * DOUT;  // 8M elems
  const size_t WSZ = (size_t)DIN * DOUT;      // 1M elems
  short* xb  = (short*)d_ws;
  short* Wqt = xb + NTD;
  short* Wkt = Wqt + WSZ;
  short* Wvt = Wkt + WSZ;
  short* Wot = Wvt + WSZ;
  short* Qb  = Wot + WSZ;
  short* Kb  = Qb + NTD;
  short* Vb  = Kb + NTD;
  short* Cb  = Vb + NTD;  // total 88 MB of ws

  const int M = Bb * Tt;  // 8192

  cvt_x<<<dim3(NTD / 1024), 256, 0, stream>>>(x, xb);
  cvt_wt<<<dim3(16, 16, 4), 256, 0, stream>>>(Wq, Wk, Wv, Wo, Wqt, Wkt, Wvt, Wot);

  dim3 gg(M / 128, DOUT / 128);  // (64, 8)
  gemm_bf16<false, false><<<gg, 256, 0, stream>>>(xb, Wqt, nullptr, Qb, M, DOUT, DIN);
  gemm_bf16<false, false><<<gg, 256, 0, stream>>>(xb, Wkt, nullptr, Kb, M, DOUT, DIN);
  gemm_bf16<false, false><<<gg, 256, 0, stream>>>(xb, Wvt, nullptr, Vb, M, DOUT, DIN);

  attn_bf16<<<dim3(Tt / 64, Bb * NH), 256, 0, stream>>>(Qb, Kb, Vb, Cb);

  gemm_bf16<true, true><<<gg, 256, 0, stream>>>(Cb, Wot, bo, out, M, DOUT, DOUT);
}

// Round 4
// 341.417 us; speedup vs baseline: 8.5802x; 1.5912x over previous
//
#include <hip/hip_runtime.h>
#include <math.h>

#define Bb   4
#define Tt   2048
#define DIN  1024
#define DOUT 1024
#define NH   16
#define HD   64

typedef __attribute__((ext_vector_type(8))) short bf16x8;
typedef __attribute__((ext_vector_type(4))) float f32x4;
typedef __attribute__((ext_vector_type(4))) short short4v;

__device__ __forceinline__ short f2bf(float f) {
  union { float f; unsigned u; } v; v.f = f;
  unsigned r = v.u + 0x7FFFu + ((v.u >> 16) & 1u);
  return (short)(r >> 16);
}

#define MFMA16(a, b, c) __builtin_amdgcn_mfma_f32_16x16x32_bf16((a), (b), (c), 0, 0, 0)

// async global->LDS, 16B per lane; LDS dest = wave-uniform base + lane*16
__device__ __forceinline__ void gload16(const short* g, short* l) {
  __builtin_amdgcn_global_load_lds(
      (const __attribute__((address_space(1))) void*)g,
      (__attribute__((address_space(3))) void*)l, 16, 0, 0);
}

// ---------------------------------------------------------------------------
// cvt_x: fp32 -> bf16
// ---------------------------------------------------------------------------
__global__ __launch_bounds__(256) void cvt_x(const float* __restrict__ x,
                                             short* __restrict__ xb) {
  const int i = (blockIdx.x * 256 + threadIdx.x) * 4;
  float4 v = *(const float4*)(x + i);
  short4v o;
  o.x = f2bf(v.x); o.y = f2bf(v.y); o.z = f2bf(v.z); o.w = f2bf(v.w);
  *(short4v*)(xb + i) = o;
}

// ---------------------------------------------------------------------------
// cvt_wt: W [K][N] fp32 -> Wt [N][K] bf16 (transpose+convert), 64x64 tiles.
// ---------------------------------------------------------------------------
__global__ __launch_bounds__(256) void cvt_wt(
    const float* __restrict__ W0, const float* __restrict__ W1,
    const float* __restrict__ W2, const float* __restrict__ W3,
    short* __restrict__ O0, short* __restrict__ O1,
    short* __restrict__ O2, short* __restrict__ O3) {
  const float* W = blockIdx.z == 0 ? W0 : blockIdx.z == 1 ? W1
                 : blockIdx.z == 2 ? W2 : W3;
  short* O = blockIdx.z == 0 ? O0 : blockIdx.z == 1 ? O1
           : blockIdx.z == 2 ? O2 : O3;
  __shared__ short t[64][65];
  const int n0 = blockIdx.x * 64, k0 = blockIdx.y * 64;
  const int tid = threadIdx.x;
#pragma unroll
  for (int i = 0; i < 16; ++i) {
    const int e = tid + 256 * i;
    const int k = e >> 6, n = e & 63;
    t[n][k] = f2bf(W[(size_t)(k0 + k) * DOUT + n0 + n]);
  }
  __syncthreads();
#pragma unroll
  for (int i = 0; i < 16; ++i) {
    const int e = tid + 256 * i;
    const int n = e >> 6, k = e & 63;
    O[(size_t)(n0 + n) * DIN + k0 + k] = t[n][k];
  }
}

// ---------------------------------------------------------------------------
// bf16 MFMA GEMM (m97-style): global_load_lds width-16 staging, linear LDS,
// inverse-swizzled source + swizzled frag reads (chunk ^= (row>>1)&3).
// BM=BN=128, BK=32, 4 waves (2x2), wave tile 64x64.
// ---------------------------------------------------------------------------
template <bool F32OUT, bool BIAS>
__global__ __launch_bounds__(256) void gemm_bf16(
    const short* __restrict__ A, const short* __restrict__ Bt,
    const float* __restrict__ bias, void* __restrict__ Cout,
    int M, int N, int K, float oscale) {
  constexpr int BM = 128, BN = 128, BK = 32;
  __shared__ __align__(16) short Asm[BM][BK];
  __shared__ __align__(16) short Bsm[BN][BK];

  const int tid = threadIdx.x;
  const int wid = tid >> 6, lane = tid & 63;
  const int lhi = lane >> 4, llo = lane & 15;
  const int bm = blockIdx.x * BM, bn = blockIdx.y * BN;
  const int wr = (wid >> 1) * 64, wc = (wid & 1) * 64;

  // staging: wave covers rows wid*32..+31, 2 issues of 16 rows x 4 chunks
  const int r0s = wid * 32 + (lane >> 2);
  const int cps = lane & 3;

  f32x4 acc[4][4];
#pragma unroll
  for (int i = 0; i < 4; ++i)
#pragma unroll
    for (int j = 0; j < 4; ++j)
#pragma unroll
      for (int r = 0; r < 4; ++r) acc[i][j][r] = 0.0f;

  for (int k0 = 0; k0 < K; k0 += BK) {
    __syncthreads();
#pragma unroll
    for (int iss = 0; iss < 2; ++iss) {
      const int ra = r0s + iss * 16;
      const int ca = (cps ^ ((ra >> 1) & 3)) * 8;  // inverse-swizzled source
      gload16(A + (size_t)(bm + ra) * K + k0 + ca, &Asm[wid * 32 + iss * 16][0]);
      gload16(Bt + (size_t)(bn + ra) * K + k0 + ca, &Bsm[wid * 32 + iss * 16][0]);
    }
    __syncthreads();

    bf16x8 af[4], bfr[4];
#pragma unroll
    for (int i = 0; i < 4; ++i) {
      const int row = wr + i * 16 + llo;
      af[i] = *(const bf16x8*)&Asm[row][(lhi ^ ((row >> 1) & 3)) * 8];
    }
#pragma unroll
    for (int j = 0; j < 4; ++j) {
      const int row = wc + j * 16 + llo;
      bfr[j] = *(const bf16x8*)&Bsm[row][(lhi ^ ((row >> 1) & 3)) * 8];
    }
#pragma unroll
    for (int i = 0; i < 4; ++i)
#pragma unroll
      for (int j = 0; j < 4; ++j)
        acc[i][j] = MFMA16(af[i], bfr[j], acc[i][j]);
  }

#pragma unroll
  for (int i = 0; i < 4; ++i)
#pragma unroll
    for (int j = 0; j < 4; ++j)
#pragma unroll
      for (int r = 0; r < 4; ++r) {
        const int row = bm + wr + i * 16 + lhi * 4 + r;
        const int col = bn + wc + j * 16 + llo;
        float v = acc[i][j][r] * oscale;
        if (BIAS) v += bias[col];
        if (F32OUT)
          ((float*)Cout)[(size_t)row * N + col] = v;
        else
          ((short*)Cout)[(size_t)row * N + col] = f2bf(v);
      }
}

// ---------------------------------------------------------------------------
// Causal flash attention, bf16 MFMA. 8 waves x 32 q-rows = 256 q-rows/block.
// KV tiles of 64, double-buffered K/V LDS (1 barrier/tile), swizzled Vt.
// Q pre-scaled by 0.125*log2e in the Q-GEMM epilogue -> exp2 directly.
// Grid: 512 blocks 1D, longest (qt=7) first.
// ---------------------------------------------------------------------------
__global__ __launch_bounds__(512, 2) void attn_bf16(
    const short* __restrict__ Q, const short* __restrict__ K,
    const short* __restrict__ V, short* __restrict__ Ctx) {
  constexpr int LDK = 72;  // shorts; 144B rows (16B-aligned, bank-balanced)
  constexpr int LDV = 72;
  constexpr int LDP = 72;
  __shared__ __align__(16) short Ks[2][64][LDK];
  __shared__ __align__(16) short Vt[2][64][LDV];  // [dim][kv], kv-chunk swizzled
  __shared__ __align__(16) short Ps[8][32][LDP];  // per-wave P

  const int bid = blockIdx.x;
  const int qt = 7 - (bid >> 6);   // longest-first
  const int bh = bid & 63;
  const int b = bh >> 4, h = bh & 15;
  const int tid = threadIdx.x;
  const int wid = tid >> 6, lane = tid & 63;
  const int lhi = lane >> 4, llo = lane & 15;

  const size_t base_bt = (size_t)b * Tt;
  const int headoff = h * HD;
  const int q0 = qt * 256 + wid * 32;   // wave's first q-row

  // ---- hoist Q fragments (rows q0+rb*16+llo, k = kf*32 + lhi*8) ----
  bf16x8 qf[2][2];
#pragma unroll
  for (int rb = 0; rb < 2; ++rb)
#pragma unroll
    for (int kf = 0; kf < 2; ++kf)
      qf[rb][kf] = *(const bf16x8*)&Q[(base_bt + q0 + rb * 16 + llo) * DOUT +
                                      headoff + kf * 32 + lhi * 8];

  float m_r[2][4], l_r[2][4];
  f32x4 oa[2][4];
#pragma unroll
  for (int rb = 0; rb < 2; ++rb)
#pragma unroll
    for (int r = 0; r < 4; ++r) { m_r[rb][r] = -1e30f; l_r[rb][r] = 0.0f; }
#pragma unroll
  for (int rb = 0; rb < 2; ++rb)
#pragma unroll
    for (int j = 0; j < 4; ++j)
#pragma unroll
      for (int r = 0; r < 4; ++r) oa[rb][j][r] = 0.0f;

  // staging map: 512 threads cover 64kv x 64d; coalesced 16B loads
  const int skv = tid >> 3;           // kv row 0..63
  const int sd0 = (tid & 7) * 8;      // dim chunk start
  const int sd3 = tid & 7;            // (sd0+e)>>3, constant
  // Vt swizzle: element (d, kv) at chunk ((kv>>3) ^ (d>>3&7)), offset kv&7
  const int vpos = (((skv >> 3) ^ sd3) * 8) + (skv & 7);

  const int ktmax = qt * 4 + 3;

  // ---- prologue: stage tile 0 into buf 0 ----
  {
    bf16x8 kreg = *(const bf16x8*)&K[(base_bt + skv) * DOUT + headoff + sd0];
    bf16x8 vreg = *(const bf16x8*)&V[(base_bt + skv) * DOUT + headoff + sd0];
    *(bf16x8*)&Ks[0][skv][sd0] = kreg;
#pragma unroll
    for (int e = 0; e < 8; ++e) Vt[0][sd0 + e][vpos] = vreg[e];
  }
  __syncthreads();

  for (int kt = 0; kt <= ktmax; ++kt) {
    const int cur = kt & 1;

    // ---- issue next-tile global loads early (T14 async-split) ----
    bf16x8 kreg, vreg;
    const bool haveNext = kt < ktmax;
    if (haveNext) {
      const size_t rbase = (base_bt + (kt + 1) * 64 + skv) * DOUT + headoff + sd0;
      kreg = *(const bf16x8*)&K[rbase];
      vreg = *(const bf16x8*)&V[rbase];
    }

    // ---- compute (waves whose rows see this tile) ----
    if (kt * 64 <= q0 + 31) {
      // K frags shared across both row-blocks
      bf16x8 kf0[4], kf1[4];
#pragma unroll
      for (int j = 0; j < 4; ++j) {
        kf0[j] = *(const bf16x8*)&Ks[cur][j * 16 + llo][lhi * 8];
        kf1[j] = *(const bf16x8*)&Ks[cur][j * 16 + llo][32 + lhi * 8];
      }

#pragma unroll
      for (int rb = 0; rb < 2; ++rb) {
        f32x4 s[4];
#pragma unroll
        for (int j = 0; j < 4; ++j) {
#pragma unroll
          for (int r = 0; r < 4; ++r) s[j][r] = 0.0f;
          s[j] = MFMA16(qf[rb][0], kf0[j], s[j]);
          s[j] = MFMA16(qf[rb][1], kf1[j], s[j]);
        }
        // causal mask (only when tile overlaps diagonal of this row-block)
        if (kt * 64 + 63 > q0 + rb * 16) {
#pragma unroll
          for (int j = 0; j < 4; ++j) {
            const int kc = kt * 64 + j * 16 + llo;
#pragma unroll
            for (int r = 0; r < 4; ++r) {
              const int qr = q0 + rb * 16 + lhi * 4 + r;
              if (kc > qr) s[j][r] = -1e30f;
            }
          }
        }
        // online softmax (rows live in 16-lane llo groups)
        float mx[4];
#pragma unroll
        for (int r = 0; r < 4; ++r)
          mx[r] = fmaxf(fmaxf(s[0][r], s[1][r]), fmaxf(s[2][r], s[3][r]));
#pragma unroll
        for (int d = 1; d < 16; d <<= 1)
#pragma unroll
          for (int r = 0; r < 4; ++r) mx[r] = fmaxf(mx[r], __shfl_xor(mx[r], d));
        float mnew[4], al[4], rs[4];
#pragma unroll
        for (int r = 0; r < 4; ++r) {
          mnew[r] = fmaxf(m_r[rb][r], mx[r]);
          al[r] = exp2f(m_r[rb][r] - mnew[r]);
          rs[r] = 0.0f;
        }
#pragma unroll
        for (int j = 0; j < 4; ++j)
#pragma unroll
          for (int r = 0; r < 4; ++r) {
            const float p = exp2f(s[j][r] - mnew[r]);
            s[j][r] = p;
            rs[r] += p;
          }
#pragma unroll
        for (int d = 1; d < 16; d <<= 1)
#pragma unroll
          for (int r = 0; r < 4; ++r) rs[r] += __shfl_xor(rs[r], d);
#pragma unroll
        for (int r = 0; r < 4; ++r) {
          l_r[rb][r] = l_r[rb][r] * al[r] + rs[r];
          m_r[rb][r] = mnew[r];
        }
#pragma unroll
        for (int j = 0; j < 4; ++j)
#pragma unroll
          for (int r = 0; r < 4; ++r) oa[rb][j][r] *= al[r];
        // P -> bf16 -> per-wave LDS (A-frag layout round-trip)
#pragma unroll
        for (int j = 0; j < 4; ++j)
#pragma unroll
          for (int r = 0; r < 4; ++r)
            Ps[wid][rb * 16 + lhi * 4 + r][j * 16 + llo] = f2bf(s[j][r]);
      }

      // ---- O += P @ V (V frags hoisted, reused across rb) ----
      bf16x8 vfr[2][4];
#pragma unroll
      for (int ks = 0; ks < 2; ++ks)
#pragma unroll
        for (int j = 0; j < 4; ++j) {
          const int d = j * 16 + llo;
          const int pos = ((lhi + 4 * ks) ^ ((d >> 3) & 7)) * 8;
          vfr[ks][j] = *(const bf16x8*)&Vt[cur][d][pos];
        }
#pragma unroll
      for (int rb = 0; rb < 2; ++rb)
#pragma unroll
        for (int ks = 0; ks < 2; ++ks) {
          bf16x8 paf = *(const bf16x8*)&Ps[wid][rb * 16 + llo][lhi * 8 + ks * 32];
#pragma unroll
          for (int j = 0; j < 4; ++j)
            oa[rb][j] = MFMA16(paf, vfr[ks][j], oa[rb][j]);
        }
    }

    // ---- write next tile into the other buffer ----
    if (haveNext) {
      const int nxt = cur ^ 1;
      *(bf16x8*)&Ks[nxt][skv][sd0] = kreg;
#pragma unroll
      for (int e = 0; e < 8; ++e) Vt[nxt][sd0 + e][vpos] = vreg[e];
    }
    __syncthreads();
  }

  // ---- finalize ----
#pragma unroll
  for (int rb = 0; rb < 2; ++rb) {
    float inv[4];
#pragma unroll
    for (int r = 0; r < 4; ++r) inv[r] = 1.0f / l_r[rb][r];
#pragma unroll
    for (int j = 0; j < 4; ++j)
#pragma unroll
      for (int r = 0; r < 4; ++r) {
        const int row = q0 + rb * 16 + lhi * 4 + r;
        const int col = headoff + j * 16 + llo;
        Ctx[(base_bt + row) * DOUT + col] = f2bf(oa[rb][j][r] * inv[r]);
      }
  }
}

// ---------------------------------------------------------------------------
extern "C" void kernel_launch(void* const* d_in, const int* in_sizes, int n_in,
                              void* d_out, int out_size, void* d_ws, size_t ws_size,
                              hipStream_t stream) {
  const float* x  = (const float*)d_in[0];
  const float* Wq = (const float*)d_in[1];
  const float* Wk = (const float*)d_in[2];
  const float* Wv = (const float*)d_in[3];
  const float* Wo = (const float*)d_in[4];
  const float* bo = (const float*)d_in[5];
  float* out = (float*)d_out;

  const size_t NTD = (size_t)Bb * Tt * DOUT;
  const size_t WSZ = (size_t)DIN * DOUT;
  short* xb  = (short*)d_ws;
  short* Wqt = xb + NTD;
  short* Wkt = Wqt + WSZ;
  short* Wvt = Wkt + WSZ;
  short* Wot = Wvt + WSZ;
  short* Qb  = Wot + WSZ;
  short* Kb  = Qb + NTD;
  short* Vb  = Kb + NTD;
  short* Cb  = Vb + NTD;

  const int M = Bb * Tt;  // 8192
  const float qscale = 0.125f * 1.44269504089f;  // 1/sqrt(HD) * log2(e)

  cvt_x<<<dim3(NTD / 1024), 256, 0, stream>>>(x, xb);
  cvt_wt<<<dim3(16, 16, 4), 256, 0, stream>>>(Wq, Wk, Wv, Wo, Wqt, Wkt, Wvt, Wot);

  dim3 gg(M / 128, DOUT / 128);  // (64, 8)
  gemm_bf16<false, false><<<gg, 256, 0, stream>>>(xb, Wqt, nullptr, Qb, M, DOUT, DIN, qscale);
  gemm_bf16<false, false><<<gg, 256, 0, stream>>>(xb, Wkt, nullptr, Kb, M, DOUT, DIN, 1.0f);
  gemm_bf16<false, false><<<gg, 256, 0, stream>>>(xb, Wvt, nullptr, Vb, M, DOUT, DIN, 1.0f);

  attn_bf16<<<dim3(512), 512, 0, stream>>>(Qb, Kb, Vb, Cb);

  gemm_bf16<true, true><<<gg, 256, 0, stream>>>(Cb, Wot, bo, out, M, DOUT, DOUT, 1.0f);
}

// Round 5
// 272.361 us; speedup vs baseline: 10.7557x; 1.2535x over previous
//
#include <hip/hip_runtime.h>
#include <math.h>

#define Bb   4
#define Tt   2048
#define DIN  1024
#define DOUT 1024
#define NH   16
#define HD   64

typedef __attribute__((ext_vector_type(8))) short bf16x8;
typedef __attribute__((ext_vector_type(4))) float f32x4;
typedef __attribute__((ext_vector_type(4))) short short4v;

__device__ __forceinline__ short f2bf(float f) {
  union { float f; unsigned u; } v; v.f = f;
  unsigned r = v.u + 0x7FFFu + ((v.u >> 16) & 1u);
  return (short)(r >> 16);
}

// packed f32x2 -> bf16x2 (RNE), single HW op on gfx950
__device__ __forceinline__ unsigned pkbf(float a, float b) {
  unsigned r;
  asm("v_cvt_pk_bf16_f32 %0, %1, %2" : "=v"(r) : "v"(a), "v"(b));
  return r;
}

#define MFMA16(a, b, c) __builtin_amdgcn_mfma_f32_16x16x32_bf16((a), (b), (c), 0, 0, 0)

// async global->LDS, 16B per lane; LDS dest = wave-uniform base + lane*16
__device__ __forceinline__ void gload16(const short* g, short* l) {
  __builtin_amdgcn_global_load_lds(
      (const __attribute__((address_space(1))) void*)g,
      (__attribute__((address_space(3))) void*)l, 16, 0, 0);
}

// ---------------------------------------------------------------------------
// cvt_x: fp32 -> bf16
// ---------------------------------------------------------------------------
__global__ __launch_bounds__(256) void cvt_x(const float* __restrict__ x,
                                             short* __restrict__ xb) {
  const int i = (blockIdx.x * 256 + threadIdx.x) * 4;
  float4 v = *(const float4*)(x + i);
  uint2 o;
  o.x = pkbf(v.x, v.y);
  o.y = pkbf(v.z, v.w);
  *(uint2*)(xb + i) = o;
}

// ---------------------------------------------------------------------------
// cvt_wt: W [K][N] fp32 -> Wt [N][K] bf16 (transpose+convert), 64x64 tiles.
// ---------------------------------------------------------------------------
__global__ __launch_bounds__(256) void cvt_wt(
    const float* __restrict__ W0, const float* __restrict__ W1,
    const float* __restrict__ W2, const float* __restrict__ W3,
    short* __restrict__ O0, short* __restrict__ O1,
    short* __restrict__ O2, short* __restrict__ O3) {
  const float* W = blockIdx.z == 0 ? W0 : blockIdx.z == 1 ? W1
                 : blockIdx.z == 2 ? W2 : W3;
  short* O = blockIdx.z == 0 ? O0 : blockIdx.z == 1 ? O1
           : blockIdx.z == 2 ? O2 : O3;
  __shared__ short t[64][65];
  const int n0 = blockIdx.x * 64, k0 = blockIdx.y * 64;
  const int tid = threadIdx.x;
#pragma unroll
  for (int i = 0; i < 16; ++i) {
    const int e = tid + 256 * i;
    const int k = e >> 6, n = e & 63;
    t[n][k] = f2bf(W[(size_t)(k0 + k) * DOUT + n0 + n]);
  }
  __syncthreads();
#pragma unroll
  for (int i = 0; i < 16; ++i) {
    const int e = tid + 256 * i;
    const int n = e >> 6, k = e & 63;
    O[(size_t)(n0 + n) * DIN + k0 + k] = t[n][k];
  }
}

// ---------------------------------------------------------------------------
// bf16 MFMA GEMM: C[M,N] = A[M,K] @ Bt^T  (Bt[N][K]).
// BM=BN=128, BK=64, 4 waves (2x2), wave tile 64x64.
// global_load_lds w16, linear LDS dest, inverse-swizzled source,
// swizzled frag reads (chunk ^= row&7). QKV mode: z-indexed Bt/C.
// ---------------------------------------------------------------------------
template <bool QKV, bool F32OUT, bool BIAS>
__global__ __launch_bounds__(256) void gemm_bf16(
    const short* __restrict__ A, const short* __restrict__ Bt0,
    const float* __restrict__ bias, void* __restrict__ Cout,
    int M, int N, int K, float qsc) {
  constexpr int BM = 128, BN = 128, BK = 64;
  __shared__ __align__(16) short Asm[BM][BK];   // 16 KB
  __shared__ __align__(16) short Bsm[BN][BK];   // 16 KB

  const short* Bt = Bt0;
  short* Cb16 = (short*)Cout;
  float oscale = 1.0f;
  if (QKV) {
    const int z = blockIdx.z;
    Bt += (size_t)z * N * K;
    Cb16 += (size_t)z * M * N;
    if (z == 0) oscale = qsc;
  }

  const int tid = threadIdx.x;
  const int wid = tid >> 6, lane = tid & 63;
  const int lhi = lane >> 4, llo = lane & 15;
  const int bm = blockIdx.x * BM, bn = blockIdx.y * BN;
  const int wr = (wid >> 1) * 64, wc = (wid & 1) * 64;

  // staging: per issue, wave covers 8 rows x 8 chunks (16B each)
  const int srow = lane >> 3;          // 0..7
  const int sca = ((lane & 7) ^ srow) * 8;  // inverse-swizzled source chunk

  f32x4 acc[4][4];
#pragma unroll
  for (int i = 0; i < 4; ++i)
#pragma unroll
    for (int j = 0; j < 4; ++j)
#pragma unroll
      for (int r = 0; r < 4; ++r) acc[i][j][r] = 0.0f;

  for (int k0 = 0; k0 < K; k0 += BK) {
    __syncthreads();
#pragma unroll
    for (int iss = 0; iss < 4; ++iss) {
      const int ra = wid * 32 + iss * 8 + srow;
      gload16(A + (size_t)(bm + ra) * K + k0 + sca, &Asm[wid * 32 + iss * 8][0]);
      gload16(Bt + (size_t)(bn + ra) * K + k0 + sca, &Bsm[wid * 32 + iss * 8][0]);
    }
    __syncthreads();

#pragma unroll
    for (int ks = 0; ks < 2; ++ks) {
      bf16x8 af[4], bfr[4];
#pragma unroll
      for (int i = 0; i < 4; ++i) {
        const int row = wr + i * 16 + llo;
        af[i] = *(const bf16x8*)&Asm[row][((ks * 4 + lhi) ^ (row & 7)) * 8];
      }
#pragma unroll
      for (int j = 0; j < 4; ++j) {
        const int row = wc + j * 16 + llo;
        bfr[j] = *(const bf16x8*)&Bsm[row][((ks * 4 + lhi) ^ (row & 7)) * 8];
      }
#pragma unroll
      for (int i = 0; i < 4; ++i)
#pragma unroll
        for (int j = 0; j < 4; ++j)
          acc[i][j] = MFMA16(af[i], bfr[j], acc[i][j]);
    }
  }

#pragma unroll
  for (int i = 0; i < 4; ++i)
#pragma unroll
    for (int j = 0; j < 4; ++j)
#pragma unroll
      for (int r = 0; r < 4; ++r) {
        const int row = bm + wr + i * 16 + lhi * 4 + r;
        const int col = bn + wc + j * 16 + llo;
        float v = acc[i][j][r] * oscale;
        if (BIAS) v += bias[col];
        if (F32OUT)
          ((float*)Cout)[(size_t)row * N + col] = v;
        else
          Cb16[(size_t)row * N + col] = f2bf(v);
      }
}

// ---------------------------------------------------------------------------
// Causal flash attention, bf16 MFMA, swapped-QK^T softmax.
// 8 waves x 32 q-rows = 256 q-rows/block; KV tiles of 64, double-buffered.
// Q pre-scaled by 0.125*log2e in Q-GEMM -> exp2 directly.
// ---------------------------------------------------------------------------
__global__ __launch_bounds__(512, 2) void attn_bf16(
    const short* __restrict__ Q, const short* __restrict__ K,
    const short* __restrict__ V, short* __restrict__ Ctx) {
  constexpr int LDK = 72;  // 144B rows: 16B-aligned, bank-balanced
  constexpr int LDV = 72;
  constexpr int LDP = 72;
  __shared__ __align__(16) short Ks[2][64][LDK];
  __shared__ __align__(16) short Vt[2][64][LDV];  // [dim][kv], kv-chunk swizzled
  __shared__ __align__(16) short Ps[8][32][LDP];  // per-wave P [q][kv]

  const int bid = blockIdx.x;
  const int qt = 7 - (bid >> 6);   // longest-first
  const int bh = bid & 63;
  const int b = bh >> 4, h = bh & 15;
  const int tid = threadIdx.x;
  const int wid = tid >> 6, lane = tid & 63;
  const int lhi = lane >> 4, llo = lane & 15;

  const size_t base_bt = (size_t)b * Tt;
  const int headoff = h * HD;
  const int q0 = qt * 256 + wid * 32;

  // Q fragments: qf[rb][kf][e] = Q[q0+rb*16+llo][kf*32+lhi*8+e] (B-operand)
  bf16x8 qf[2][2];
#pragma unroll
  for (int rb = 0; rb < 2; ++rb)
#pragma unroll
    for (int kf = 0; kf < 2; ++kf)
      qf[rb][kf] = *(const bf16x8*)&Q[(base_bt + q0 + rb * 16 + llo) * DOUT +
                                      headoff + kf * 32 + lhi * 8];

  // softmax stats per-lane (q = q0 + rb*16 + llo)
  float m_r[2] = {-1e30f, -1e30f}, l_r[2] = {0.0f, 0.0f};
  f32x4 oa[2][4];
#pragma unroll
  for (int rb = 0; rb < 2; ++rb)
#pragma unroll
    for (int j = 0; j < 4; ++j)
#pragma unroll
      for (int r = 0; r < 4; ++r) oa[rb][j][r] = 0.0f;

  // staging map: 512 threads cover 64kv x 64d
  const int skv = tid >> 3;
  const int sd0 = (tid & 7) * 8;
  const int sd3 = tid & 7;
  const int vpos = (((skv >> 3) ^ sd3) * 8) + (skv & 7);

  const int ktmax = qt * 4 + 3;

  {  // prologue: stage tile 0 into buf 0
    bf16x8 kreg = *(const bf16x8*)&K[(base_bt + skv) * DOUT + headoff + sd0];
    bf16x8 vreg = *(const bf16x8*)&V[(base_bt + skv) * DOUT + headoff + sd0];
    *(bf16x8*)&Ks[0][skv][sd0] = kreg;
#pragma unroll
    for (int e = 0; e < 8; ++e) Vt[0][sd0 + e][vpos] = vreg[e];
  }
  __syncthreads();

  for (int kt = 0; kt <= ktmax; ++kt) {
    const int cur = kt & 1;

    bf16x8 kreg, vreg;
    const bool haveNext = kt < ktmax;
    if (haveNext) {
      const size_t rbase = (base_bt + (kt + 1) * 64 + skv) * DOUT + headoff + sd0;
      kreg = *(const bf16x8*)&K[rbase];
      vreg = *(const bf16x8*)&V[rbase];
    }

    if (kt * 64 <= q0 + 31) {
      bf16x8 kf0[4], kf1[4];
#pragma unroll
      for (int j = 0; j < 4; ++j) {
        kf0[j] = *(const bf16x8*)&Ks[cur][j * 16 + llo][lhi * 8];
        kf1[j] = *(const bf16x8*)&Ks[cur][j * 16 + llo][32 + lhi * 8];
      }

#pragma unroll
      for (int rb = 0; rb < 2; ++rb) {
        // S^T = K @ Q^T : s[j][r] = S[q=llo][kv=j*16+lhi*4+r]
        f32x4 s[4];
#pragma unroll
        for (int j = 0; j < 4; ++j) {
#pragma unroll
          for (int r = 0; r < 4; ++r) s[j][r] = 0.0f;
          s[j] = MFMA16(kf0[j], qf[rb][0], s[j]);
          s[j] = MFMA16(kf1[j], qf[rb][1], s[j]);
        }
        // causal mask
        if (kt * 64 + 63 > q0 + rb * 16) {
          const int qr = q0 + rb * 16 + llo;
#pragma unroll
          for (int j = 0; j < 4; ++j)
#pragma unroll
            for (int r = 0; r < 4; ++r)
              if (kt * 64 + j * 16 + lhi * 4 + r > qr) s[j][r] = -1e30f;
        }
        // in-lane row max (tree) + 2 cross-group shuffles
        float a0 = fmaxf(fmaxf(s[0][0], s[0][1]), fmaxf(s[0][2], s[0][3]));
        float a1 = fmaxf(fmaxf(s[1][0], s[1][1]), fmaxf(s[1][2], s[1][3]));
        float a2 = fmaxf(fmaxf(s[2][0], s[2][1]), fmaxf(s[2][2], s[2][3]));
        float a3 = fmaxf(fmaxf(s[3][0], s[3][1]), fmaxf(s[3][2], s[3][3]));
        float mx = fmaxf(fmaxf(a0, a1), fmaxf(a2, a3));
        mx = fmaxf(mx, __shfl_xor(mx, 16));
        mx = fmaxf(mx, __shfl_xor(mx, 32));
        // defer-max: rescale only when max grew beyond threshold
        if (!__all(mx - m_r[rb] <= 8.0f)) {
          const float mnew = fmaxf(m_r[rb], mx);
          const float al = exp2f(m_r[rb] - mnew);
          m_r[rb] = mnew;
          l_r[rb] *= al;
          float alr[4];
#pragma unroll
          for (int r = 0; r < 4; ++r) alr[r] = __shfl(al, (lhi << 2) | r, 16);
#pragma unroll
          for (int j = 0; j < 4; ++j)
#pragma unroll
            for (int r = 0; r < 4; ++r) oa[rb][j][r] *= alr[r];
        }
        const float mc = m_r[rb];
#pragma unroll
        for (int j = 0; j < 4; ++j)
#pragma unroll
          for (int r = 0; r < 4; ++r) s[j][r] = exp2f(s[j][r] - mc);
        float b0 = (s[0][0] + s[0][1]) + (s[0][2] + s[0][3]);
        float b1 = (s[1][0] + s[1][1]) + (s[1][2] + s[1][3]);
        float b2 = (s[2][0] + s[2][1]) + (s[2][2] + s[2][3]);
        float b3 = (s[3][0] + s[3][1]) + (s[3][2] + s[3][3]);
        float rs = (b0 + b1) + (b2 + b3);
        rs += __shfl_xor(rs, 16);
        rs += __shfl_xor(rs, 32);
        l_r[rb] += rs;
        // pack P -> bf16 pairs -> per-wave LDS [q][kv]
#pragma unroll
        for (int j = 0; j < 4; ++j) {
          uint2 w;
          w.x = pkbf(s[j][0], s[j][1]);
          w.y = pkbf(s[j][2], s[j][3]);
          *(uint2*)&Ps[wid][rb * 16 + llo][j * 16 + lhi * 4] = w;
        }
      }

      // O += P @ V
      bf16x8 vfr[2][4];
#pragma unroll
      for (int ks = 0; ks < 2; ++ks)
#pragma unroll
        for (int j = 0; j < 4; ++j) {
          const int d = j * 16 + llo;
          const int pos = ((lhi + 4 * ks) ^ ((d >> 3) & 7)) * 8;
          vfr[ks][j] = *(const bf16x8*)&Vt[cur][d][pos];
        }
#pragma unroll
      for (int rb = 0; rb < 2; ++rb)
#pragma unroll
        for (int ks = 0; ks < 2; ++ks) {
          bf16x8 paf = *(const bf16x8*)&Ps[wid][rb * 16 + llo][lhi * 8 + ks * 32];
#pragma unroll
          for (int j = 0; j < 4; ++j)
            oa[rb][j] = MFMA16(paf, vfr[ks][j], oa[rb][j]);
        }
    }

    if (haveNext) {
      const int nxt = cur ^ 1;
      *(bf16x8*)&Ks[nxt][skv][sd0] = kreg;
#pragma unroll
      for (int e = 0; e < 8; ++e) Vt[nxt][sd0 + e][vpos] = vreg[e];
    }
    __syncthreads();
  }

  // finalize: redistribute 1/l from llo-layout to (lhi,r)-layout, store
#pragma unroll
  for (int rb = 0; rb < 2; ++rb) {
    const float linv = 1.0f / l_r[rb];
    float lr[4];
#pragma unroll
    for (int r = 0; r < 4; ++r) lr[r] = __shfl(linv, (lhi << 2) | r, 16);
#pragma unroll
    for (int j = 0; j < 4; ++j)
#pragma unroll
      for (int r = 0; r < 4; ++r) {
        const int row = q0 + rb * 16 + lhi * 4 + r;
        const int col = headoff + j * 16 + llo;
        Ctx[(base_bt + row) * DOUT + col] = f2bf(oa[rb][j][r] * lr[r]);
      }
  }
}

// ---------------------------------------------------------------------------
extern "C" void kernel_launch(void* const* d_in, const int* in_sizes, int n_in,
                              void* d_out, int out_size, void* d_ws, size_t ws_size,
                              hipStream_t stream) {
  const float* x  = (const float*)d_in[0];
  const float* Wq = (const float*)d_in[1];
  const float* Wk = (const float*)d_in[2];
  const float* Wv = (const float*)d_in[3];
  const float* Wo = (const float*)d_in[4];
  const float* bo = (const float*)d_in[5];
  float* out = (float*)d_out;

  const size_t NTD = (size_t)Bb * Tt * DOUT;
  const size_t WSZ = (size_t)DIN * DOUT;
  short* xb  = (short*)d_ws;
  short* Wqt = xb + NTD;
  short* Wkt = Wqt + WSZ;   // Wqt/Wkt/Wvt contiguous (QKV z-indexing)
  short* Wvt = Wkt + WSZ;
  short* Wot = Wvt + WSZ;
  short* Qb  = Wot + WSZ;   // Qb/Kb/Vb contiguous (QKV z-indexing)
  short* Kb  = Qb + NTD;
  short* Vb  = Kb + NTD;
  short* Cb  = Vb + NTD;

  const int M = Bb * Tt;  // 8192
  const float qscale = 0.125f * 1.44269504089f;  // 1/sqrt(HD) * log2(e)

  cvt_x<<<dim3(NTD / 1024), 256, 0, stream>>>(x, xb);
  cvt_wt<<<dim3(16, 16, 4), 256, 0, stream>>>(Wq, Wk, Wv, Wo, Wqt, Wkt, Wvt, Wot);

  gemm_bf16<true, false, false><<<dim3(64, 8, 3), 256, 0, stream>>>(
      xb, Wqt, nullptr, Qb, M, DOUT, DIN, qscale);

  attn_bf16<<<dim3(512), 512, 0, stream>>>(Qb, Kb, Vb, Cb);

  gemm_bf16<false, true, true><<<dim3(64, 8), 256, 0, stream>>>(
      Cb, Wot, bo, out, M, DOUT, DOUT, 1.0f);
}